// Round 8
// baseline (317.255 us; speedup 1.0000x reference)
//
#include <hip/hip_runtime.h>
#include <hip/hip_bf16.h>

typedef unsigned short u16;
typedef unsigned int u32;
typedef long long i64;
typedef __attribute__((ext_vector_type(8))) short s8v;    // 8 bf16 (4 VGPRs)
typedef __attribute__((ext_vector_type(4))) float f32x4;  // MFMA acc

#define BKT_CAP 8184   // slots per coarse bucket (mean ~4092 -> 64 sigma headroom)

__device__ __forceinline__ float bf2f(u16 u) {
    union { u32 i; float f; } x; x.i = ((u32)u) << 16; return x.f;
}
__device__ __forceinline__ u16 f2bf(float f) {
    union { float f; u32 i; } x; x.f = f;
    u32 v = x.i;
    u32 r = v + 0x7FFFu + ((v >> 16) & 1u);   // RNE
    return (u16)(r >> 16);
}
__device__ __forceinline__ int get_i(const void* p, size_t i, int m64) {
    return m64 ? (int)((const i64*)p)[i] : ((const int*)p)[i];
}
__device__ __forceinline__ float lrelu_clamp(float v) {
    v = v > 0.f ? v : 0.2f * v;
    return fminf(v, 80.f);
}

// ---------------------------------------------------------------------------
// k_init: block 0 = dtype detect; blocks 1..64 = W transpose (bf16 path);
// all blocks stride-zero bucket_cnt[].
// ---------------------------------------------------------------------------
__global__ __launch_bounds__(256) void k_init(
    const u16* __restrict__ hin, const int* __restrict__ eidx, int* __restrict__ flags,
    const u16* __restrict__ W, u16* __restrict__ Wt, int* __restrict__ bucket_cnt, int nbk)
{
    const int b = blockIdx.x, t = threadIdx.x;
    if (b == 0) {
        __shared__ int c1, c2;
        if (t == 0) { c1 = 0; c2 = 0; }
        __syncthreads();
        int l1 = 0, l2 = 0;
        for (int i = t; i < 8192; i += 256) {
            float v = bf2f(hin[i]);
            if (!(fabsf(v) <= 100.f)) l1++;
            if ((i & 1) && eidx[i] == 0) l2++;
        }
        atomicAdd(&c1, l1); atomicAdd(&c2, l2);
        __syncthreads();
        if (t == 0) {
            flags[0] = (c1 > 40) ? 1 : 0;
            flags[1] = (c2 > 3000) ? 1 : 0;
        }
    } else {
        // Wt[n][k] = W[k][n] (garbage in fp32 mode; never read there).
        int i = (b - 1) * 256 + t;
        int k = i >> 7, n = i & 127;
        Wt[(size_t)n * 128 + k] = W[(size_t)k * 128 + n];
    }
    for (int i = b * 256 + t; i < nbk; i += gridDim.x * 256) bucket_cnt[i] = 0;
}

// ---------------------------------------------------------------------------
// k_bktA: coarse-bucket edges by tgt>>8. Blocks stage 4096 edges in LDS,
// LDS-histogram over buckets, ONE global atomicAdd per (block,bucket) to
// reserve space, then place (src,tgt) pairs into per-bucket arrays.
// ---------------------------------------------------------------------------
__global__ __launch_bounds__(256) void k_bktA(
    const void* __restrict__ eidx, const int* __restrict__ flags,
    int* __restrict__ bucket_cnt, int2* __restrict__ bkt,
    int n_edges, int n_nodes, int nbk)
{
    __shared__ int2 ed[4096];
    __shared__ int lcnt[512];
    __shared__ int lpos[512];
    const int t = threadIdx.x;
    const int e0 = blockIdx.x * 4096;
    const int m64 = flags[1];
    const int nloc = min(4096, n_edges - e0);

    for (int i = t; i < 512; i += 256) lcnt[i] = 0;
    __syncthreads();

    for (int r = 0; r < 16; r++) {
        int i = r * 256 + t;
        if (i < nloc) {
            int e = e0 + i;
            int s  = get_i(eidx, e, m64);
            int tg = get_i(eidx, (size_t)n_edges + e, m64);
            s  = min(max(s, 0), n_nodes - 1);
            tg = min(max(tg, 0), n_nodes - 1);
            ed[i] = make_int2(s, tg);
            atomicAdd(&lcnt[tg >> 8], 1);
        }
    }
    __syncthreads();

    for (int bb = t; bb < nbk; bb += 256) {
        int c = lcnt[bb];
        lpos[bb] = c ? atomicAdd(&bucket_cnt[bb], c) : 0;
    }
    __syncthreads();

    for (int r = 0; r < 16; r++) {
        int i = r * 256 + t;
        if (i < nloc) {
            int2 st = ed[i];
            int bb = st.y >> 8;
            int p = atomicAdd(&lpos[bb], 1);
            p = min(p, BKT_CAP - 1);              // pathological-input clamp
            bkt[(size_t)bb * BKT_CAP + p] = st;
        }
    }
}

// ---------------------------------------------------------------------------
// k_bsort: block = bucket. Redundant 512-wide LDS scan of bucket counts ->
// global segment base; LDS counting sort over the bucket's 256 targets;
// writes offs[] and src_sorted[] into a ~16KB XCD-local window.
// ---------------------------------------------------------------------------
__global__ __launch_bounds__(256) void k_bsort(
    const int* __restrict__ bucket_cnt, const int2* __restrict__ bkt,
    int* __restrict__ offs, int* __restrict__ src_sorted,
    int n_edges, int n_nodes, int nbk)
{
    __shared__ int s_a[512], s_b[512];
    __shared__ int tcnt[256], tpos[256];
    const int t = threadIdx.x;
    const int b = blockIdx.x;

    // ---- 512-wide inclusive scan of clamped bucket counts (ping-pong)
    for (int i = t; i < 512; i += 256)
        s_a[i] = (i < nbk) ? min(bucket_cnt[i], BKT_CAP) : 0;
    __syncthreads();
    int* pa = s_a; int* pb = s_b;
    for (int off = 1; off < 512; off <<= 1) {
        #pragma unroll
        for (int k = 0; k < 2; k++) {
            int i = t + k * 256;
            pb[i] = pa[i] + (i >= off ? pa[i - off] : 0);
        }
        __syncthreads();
        int* sw = pa; pa = pb; pb = sw;
    }
    const int cnt_b = min(bucket_cnt[b], BKT_CAP);
    const int Gb    = pa[b] - cnt_b;       // exclusive prefix = my segment base
    const int total = pa[511];
    __syncthreads();                        // all reads of pa done before reuse

    // ---- per-target histogram within bucket
    tcnt[t] = 0;
    __syncthreads();
    const int2* mybkt = bkt + (size_t)b * BKT_CAP;
    for (int i = t; i < cnt_b; i += 256)
        atomicAdd(&tcnt[mybkt[i].y & 255], 1);
    __syncthreads();

    // ---- exclusive scan of tcnt
    int own = tcnt[t];
    s_a[t] = own;
    __syncthreads();
    for (int off = 1; off < 256; off <<= 1) {
        int x = (t >= off) ? s_a[t - off] : 0;
        __syncthreads();
        s_a[t] += x;
        __syncthreads();
    }
    const int texcl = s_a[t] - own;

    // ---- offs + placement
    const int tgt_id = b * 256 + t;
    if (tgt_id < n_nodes) offs[tgt_id] = Gb + texcl;
    if (b == 0 && t == 0) offs[n_nodes] = total;
    tpos[t] = Gb + texcl;
    __syncthreads();
    for (int i = t; i < cnt_b; i += 256) {
        int2 st = mybkt[i];
        int p = atomicAdd(&tpos[st.y & 255], 1);
        src_sorted[p] = st.x;
    }
}

// ---------------------------------------------------------------------------
// MFMA projection (true-bf16-input mode): hp PERMUTED bf16
// (hp[row*128 + col*8 + ct] = h_proj[row][ct*16+col]) + ssrc/stgt [N][4].
// ---------------------------------------------------------------------------
__global__ __launch_bounds__(256) void k_proj_mfma(
    const u16* __restrict__ hin, const u16* __restrict__ Wt,
    const u16* __restrict__ bias, const u16* __restrict__ a_src,
    const u16* __restrict__ a_tgt, const int* __restrict__ flags,
    u16* __restrict__ hp, float* __restrict__ ssrc, float* __restrict__ stgt,
    int M)
{
    if (flags[0]) return;   // fp32 handled by k_proj_f32
    const int wave = threadIdx.x >> 6;
    const int lane = threadIdx.x & 63;
    const int q = lane >> 4, col = lane & 15;
    const int row0 = blockIdx.x * 64 + wave * 16;
    if (row0 >= M) return;

    const int arow = min(row0 + col, M - 1);
    f32x4 acc[8];
    #pragma unroll
    for (int ct = 0; ct < 8; ct++) acc[ct] = (f32x4){0.f, 0.f, 0.f, 0.f};

    #pragma unroll
    for (int kc = 0; kc < 4; kc++) {
        s8v afrag = *(const s8v*)(hin + (size_t)arow * 128 + kc * 32 + q * 8);
        #pragma unroll
        for (int ct = 0; ct < 8; ct++) {
            s8v bfrag = *(const s8v*)(Wt + (size_t)(ct * 16 + col) * 128 + kc * 32 + q * 8);
            acc[ct] = __builtin_amdgcn_mfma_f32_16x16x32_bf16(afrag, bfrag, acc[ct], 0, 0, 0);
        }
    }

    float bb[8], as[8], at[8];
    #pragma unroll
    for (int ct = 0; ct < 8; ct++) {
        int c = ct * 16 + col;
        bb[ct] = bf2f(bias[c]);
        as[ct] = bf2f(a_src[c]);
        at[ct] = bf2f(a_tgt[c]);
    }

    #pragma unroll
    for (int r = 0; r < 4; r++) {
        int row = row0 + q * 4 + r;
        float ps0 = 0.f, ps1 = 0.f, ps2 = 0.f, ps3 = 0.f;
        float pt0 = 0.f, pt1 = 0.f, pt2 = 0.f, pt3 = 0.f;
        float ov[8];
        #pragma unroll
        for (int ct = 0; ct < 8; ct++) {
            float v = acc[ct][r] + bb[ct];
            ov[ct] = v;
            float s = v * as[ct], t2 = v * at[ct];
            if (ct < 2)      { ps0 += s; pt0 += t2; }
            else if (ct < 4) { ps1 += s; pt1 += t2; }
            else if (ct < 6) { ps2 += s; pt2 += t2; }
            else             { ps3 += s; pt3 += t2; }
        }
        if (row < M) {
            union { ushort4 h[2]; uint4 qv; } pk;
            pk.h[0] = make_ushort4(f2bf(ov[0]), f2bf(ov[1]), f2bf(ov[2]), f2bf(ov[3]));
            pk.h[1] = make_ushort4(f2bf(ov[4]), f2bf(ov[5]), f2bf(ov[6]), f2bf(ov[7]));
            *(uint4*)(hp + (size_t)row * 128 + col * 8) = pk.qv;
        }
        #pragma unroll
        for (int m = 1; m < 16; m <<= 1) {
            ps0 += __shfl_xor(ps0, m); ps1 += __shfl_xor(ps1, m);
            ps2 += __shfl_xor(ps2, m); ps3 += __shfl_xor(ps3, m);
            pt0 += __shfl_xor(pt0, m); pt1 += __shfl_xor(pt1, m);
            pt2 += __shfl_xor(pt2, m); pt3 += __shfl_xor(pt3, m);
        }
        if (row < M && col < 4) {
            float vs = col == 0 ? ps0 : col == 1 ? ps1 : col == 2 ? ps2 : ps3;
            float vt = col == 0 ? pt0 : col == 1 ? pt1 : col == 2 ? pt2 : pt3;
            ssrc[(size_t)row * 4 + col] = vs;
            stgt[(size_t)row * 4 + col] = vt;
        }
    }
}

// ---------------------------------------------------------------------------
// Vector projection (fp32 inputs — THE LIVE PATH). R7 change: LDS W-TILING.
// The old inner loop re-fetched W from global every k-iter (~0.8-1.6 GB of
// L2 reads per launch for a 64 KB matrix). Now: tile k by 32, stage the
// 32x128 fp32 W-tile (16 KB) in LDS once, read w4 from LDS. Identical FMA
// order -> bit-identical results. LDS 24.5->40.5 KB (3 blocks/CU), fine
// since the global-load latency is gone. Scores fp32 exact; table stored
// PERMUTED BF16 (same layout as MFMA path).
// ---------------------------------------------------------------------------
__global__ __launch_bounds__(256) void k_proj_f32(
    const float* __restrict__ hin, const float* __restrict__ W,
    const float* __restrict__ bias, const float* __restrict__ a_src,
    const float* __restrict__ a_tgt, const int* __restrict__ flags,
    u16* __restrict__ hp, float* __restrict__ ssrc, float* __restrict__ stgt,
    int n_nodes)
{
    if (!flags[0]) return;
    __shared__ float hs[32][128];     // 16 KB input tile
    __shared__ float ws[32][128];     // 16 KB W k-tile
    __shared__ u16 sh_hp[32][128];    // 8 KB permuted bf16 out
    __shared__ float sh_s[32][4], sh_t[32][4];
    const int t = threadIdx.x;
    const int row0 = blockIdx.x * 32;

    for (int i = t; i < 32 * 64; i += 256) {
        int r = i >> 6, kk = (i & 63) * 2;
        int row = row0 + r;
        float2 v = (row < n_nodes) ? *(const float2*)(hin + (size_t)row * 128 + kk)
                                   : make_float2(0.f, 0.f);
        hs[r][kk] = v.x; hs[r][kk + 1] = v.y;
    }

    const int cg = (t & 31) * 4;
    const int rg = (t >> 5) * 4;
    float acc[4][4] = {};
    for (int kt = 0; kt < 128; kt += 32) {
        __syncthreads();   // 1st iter: hs ready; later: ws readers done
        // stage W rows kt..kt+31 (4096 floats = 1024 float4), coalesced
        for (int i = t; i < 1024; i += 256) {
            int kk = i >> 5, c4 = (i & 31) * 4;
            *(float4*)&ws[kk][c4] = *(const float4*)(W + (size_t)(kt + kk) * 128 + c4);
        }
        __syncthreads();
        for (int kk = 0; kk < 32; kk += 4) {
            float4 h0 = *(const float4*)&hs[rg + 0][kt + kk];
            float4 h1 = *(const float4*)&hs[rg + 1][kt + kk];
            float4 h2 = *(const float4*)&hs[rg + 2][kt + kk];
            float4 h3 = *(const float4*)&hs[rg + 3][kt + kk];
            #pragma unroll
            for (int j = 0; j < 4; j++) {
                float4 w4 = *(const float4*)&ws[kk + j][cg];
                float hh0 = ((const float*)&h0)[j], hh1 = ((const float*)&h1)[j];
                float hh2 = ((const float*)&h2)[j], hh3 = ((const float*)&h3)[j];
                acc[0][0] += hh0 * w4.x; acc[0][1] += hh0 * w4.y; acc[0][2] += hh0 * w4.z; acc[0][3] += hh0 * w4.w;
                acc[1][0] += hh1 * w4.x; acc[1][1] += hh1 * w4.y; acc[1][2] += hh1 * w4.z; acc[1][3] += hh1 * w4.w;
                acc[2][0] += hh2 * w4.x; acc[2][1] += hh2 * w4.y; acc[2][2] += hh2 * w4.z; acc[2][3] += hh2 * w4.w;
                acc[3][0] += hh3 * w4.x; acc[3][1] += hh3 * w4.y; acc[3][2] += hh3 * w4.z; acc[3][3] += hh3 * w4.w;
            }
        }
    }
    float b0 = bias[cg], b1 = bias[cg + 1], b2 = bias[cg + 2], b3 = bias[cg + 3];
    #pragma unroll
    for (int i = 0; i < 4; i++) {
        acc[i][0] += b0; acc[i][1] += b1; acc[i][2] += b2; acc[i][3] += b3;
    }
    // stage permuted bf16: feature f -> permuted pos (f&15)*8 + (f>>4)
    #pragma unroll
    for (int i = 0; i < 4; i++) {
        #pragma unroll
        for (int j = 0; j < 4; j++) {
            int f = cg + j;
            sh_hp[rg + i][(f & 15) * 8 + (f >> 4)] = f2bf(acc[i][j]);
        }
    }
    const int head = cg >> 5;
    float as0 = a_src[cg], as1 = a_src[cg + 1], as2 = a_src[cg + 2], as3 = a_src[cg + 3];
    float at0 = a_tgt[cg], at1 = a_tgt[cg + 1], at2 = a_tgt[cg + 2], at3 = a_tgt[cg + 3];
    float p1[4], p2[4];
    #pragma unroll
    for (int i = 0; i < 4; i++) {
        p1[i] = acc[i][0] * as0 + acc[i][1] * as1 + acc[i][2] * as2 + acc[i][3] * as3;
        p2[i] = acc[i][0] * at0 + acc[i][1] * at1 + acc[i][2] * at2 + acc[i][3] * at3;
    }
    #pragma unroll
    for (int m = 1; m < 8; m <<= 1) {
        #pragma unroll
        for (int i = 0; i < 4; i++) {
            p1[i] += __shfl_xor(p1[i], m);
            p2[i] += __shfl_xor(p2[i], m);
        }
    }
    if ((t & 7) == 0) {
        #pragma unroll
        for (int i = 0; i < 4; i++) { sh_s[rg + i][head] = p1[i]; sh_t[rg + i][head] = p2[i]; }
    }
    __syncthreads();
    // coalesced permuted-bf16 table store: 512 uint4 chunks (32 rows x 16)
    for (int c = t; c < 512; c += 256) {
        int r = c >> 4, off = (c & 15) * 8;
        int row = row0 + r;
        if (row < n_nodes)
            *(uint4*)(hp + (size_t)row * 128 + off) = *(const uint4*)&sh_hp[r][off];
    }
    if (t < 128) {
        int r = t >> 2, h = t & 3;
        int row = row0 + r;
        if (row < n_nodes) ssrc[(size_t)row * 4 + h] = sh_s[r][h];
    } else {
        int r = (t - 128) >> 2, h = t & 3;
        int row = row0 + r;
        if (row < n_nodes) stgt[(size_t)row * 4 + h] = sh_t[r][h];
    }
}

// ---------------------------------------------------------------------------
// Aggregation (unified): wave per target; permuted-bf16 table gather in BOTH
// modes (256B/edge). Phase 1: lane=edge, one coalesced index load + 4 exps
// per edge ONCE; phase 2: 16 static 4-edge slots, depth-8 pipeline, weights
// via __shfl. Only the final store differs by output dtype.
// ---------------------------------------------------------------------------
__global__ __launch_bounds__(256) void k_agg_csr(
    const int* __restrict__ offs, const int* __restrict__ src_sorted,
    const float* __restrict__ ssrc, const float* __restrict__ stgt,
    const void* __restrict__ hp, void* __restrict__ out,
    const int* __restrict__ flags, int n_nodes)
{
    __shared__ u16 ob[4][128];
    __shared__ float obf[4][128];
    const int wave = threadIdx.x >> 6;
    int wid = (blockIdx.x * 256 + threadIdx.x) >> 6;
    wid = min(wid, n_nodes - 1);          // clamp (dup waves benign) -> barrier-safe
    const int lane = threadIdx.x & 63;
    const int fp32 = flags[0];
    const int d0 = offs[wid], d1 = offs[wid + 1];

    const int sub = lane >> 4;    // edge slot 0..3 within a 4-edge group
    const int li = lane & 15;     // uint4 of 8 permuted bf16 feats
    const u16* hpb = (const u16*)hp;
    const float4* ssrc4 = (const float4*)ssrc;
    const float4 st4 = ((const float4*)stgt)[wid];
    const int deg = d1 - d0;

    float a[8] = {};
    auto accum = [&](float4 w, uint4 v) {
        a[0] += w.x * bf2f((u16)(v.x & 0xffff));
        a[1] += w.x * bf2f((u16)(v.x >> 16));
        a[2] += w.y * bf2f((u16)(v.y & 0xffff));
        a[3] += w.y * bf2f((u16)(v.y >> 16));
        a[4] += w.z * bf2f((u16)(v.z & 0xffff));
        a[5] += w.z * bf2f((u16)(v.z >> 16));
        a[6] += w.w * bf2f((u16)(v.w & 0xffff));
        a[7] += w.w * bf2f((u16)(v.w >> 16));
    };

    // ---- phase 1: lane = edge; index + weight for first min(deg,64) edges
    const int nh = min(deg, 64);
    int my_s = 0;
    float4 my_w = make_float4(0.f, 0.f, 0.f, 0.f);
    if (nh > 0) {
        my_s = src_sorted[d0 + min(lane, nh - 1)];   // one coalesced load
        float4 cs = ssrc4[my_s];
        if (lane < nh) {
            my_w = make_float4(__expf(lrelu_clamp(cs.x + st4.x)),
                               __expf(lrelu_clamp(cs.y + st4.y)),
                               __expf(lrelu_clamp(cs.z + st4.z)),
                               __expf(lrelu_clamp(cs.w + st4.w)));
        }
    }

    // ---- phase 2: statically-pipelined row gather, 4 edges per slot
    const int ns = (nh + 3) >> 2;          // 0..16 slots (wave-uniform)
    auto sload = [&](int k, uint4& vv) {
        if (k < ns) {
            int s = __shfl(my_s, k * 4 + sub);
            vv = *(const uint4*)(hpb + (size_t)s * 128 + li * 8);
        }
    };
    auto sacc = [&](int k, uint4 vv) {
        if (k < ns) {
            int idx = k * 4 + sub;
            float4 w;
            w.x = __shfl(my_w.x, idx);
            w.y = __shfl(my_w.y, idx);
            w.z = __shfl(my_w.z, idx);
            w.w = __shfl(my_w.w, idx);
            accum(w, vv);
        }
    };
    uint4 v0{}, v1{}, v2{}, v3{}, v4{}, v5{}, v6{}, v7{};
    sload(0, v0); sload(1, v1); sload(2, v2); sload(3, v3);
    sload(4, v4); sload(5, v5); sload(6, v6); sload(7, v7);
    sacc(0, v0); sload(8, v0);
    sacc(1, v1); sload(9, v1);
    sacc(2, v2); sload(10, v2);
    sacc(3, v3); sload(11, v3);
    sacc(4, v4); sload(12, v4);
    sacc(5, v5); sload(13, v5);
    sacc(6, v6); sload(14, v6);
    sacc(7, v7); sload(15, v7);
    sacc(8, v0); sacc(9, v1); sacc(10, v2); sacc(11, v3);
    sacc(12, v4); sacc(13, v5); sacc(14, v6); sacc(15, v7);

    // ---- tail (deg > 64): per-group gather; ~never taken for Poisson(16)
    float4 es_t = make_float4(0.f, 0.f, 0.f, 0.f);
    if (deg > 64) {
        for (int e = d0 + 64; e < d1; e += 4) {
            int idx = e + sub;
            int ok = idx < d1;
            int s = src_sorted[ok ? idx : d1 - 1];
            uint4 v = *(const uint4*)(hpb + (size_t)s * 128 + li * 8);
            float4 cs = ssrc4[s];
            float4 w = make_float4(__expf(lrelu_clamp(cs.x + st4.x)),
                                   __expf(lrelu_clamp(cs.y + st4.y)),
                                   __expf(lrelu_clamp(cs.z + st4.z)),
                                   __expf(lrelu_clamp(cs.w + st4.w)));
            if (!ok) w = make_float4(0.f, 0.f, 0.f, 0.f);
            accum(w, v);
            es_t.x += w.x; es_t.y += w.y; es_t.z += w.z; es_t.w += w.w;
        }
    }

    // ---- denominator: reduce head weights within 16-lane groups first
    float4 es = my_w;
    #pragma unroll
    for (int m = 1; m < 16; m <<= 1) {
        es.x += __shfl_xor(es.x, m);
        es.y += __shfl_xor(es.y, m);
        es.z += __shfl_xor(es.z, m);
        es.w += __shfl_xor(es.w, m);
    }
    es.x += es_t.x; es.y += es_t.y; es.z += es_t.z; es.w += es_t.w;

    // ---- combine 4 edge slots (xor over lane bits 4,5 keeps li fixed)
    #pragma unroll
    for (int m = 0; m < 8; m++) {
        a[m] += __shfl_xor(a[m], 16);
        a[m] += __shfl_xor(a[m], 32);
    }
    es.x += __shfl_xor(es.x, 16); es.x += __shfl_xor(es.x, 32);
    es.y += __shfl_xor(es.y, 16); es.y += __shfl_xor(es.y, 32);
    es.z += __shfl_xor(es.z, 16); es.z += __shfl_xor(es.z, 32);
    es.w += __shfl_xor(es.w, 16); es.w += __shfl_xor(es.w, 32);

    float inv4[4] = {1.f / (es.x + 1e-16f), 1.f / (es.y + 1e-16f),
                     1.f / (es.z + 1e-16f), 1.f / (es.w + 1e-16f)};

    if (!fp32) {
        if (sub == 0) {
            #pragma unroll
            for (int m = 0; m < 8; m++)
                ob[wave][m * 16 + li] = f2bf(a[m] * inv4[m >> 1]);   // c = m*16+li
        }
        __syncthreads();
        if (sub == 0) {
            uint4 ov = *(const uint4*)&ob[wave][li * 8];             // un-permuted 16B
            *(uint4*)((u16*)out + (size_t)wid * 128 + li * 8) = ov;
        }
    } else {
        if (sub == 0) {
            #pragma unroll
            for (int m = 0; m < 8; m++)
                obf[wave][m * 16 + li] = a[m] * inv4[m >> 1];
        }
        __syncthreads();
        float* of = (float*)out + (size_t)wid * 128;
        *(float2*)(of + lane * 2) = make_float2(obf[wave][lane * 2],
                                                obf[wave][lane * 2 + 1]);
    }
}

extern "C" void kernel_launch(void* const* d_in, const int* in_sizes, int n_in,
                              void* d_out, int out_size, void* d_ws, size_t ws_size,
                              hipStream_t stream)
{
    const void* h_in  = d_in[0];
    const void* eidx  = d_in[1];
    const void* W     = d_in[2];
    const void* bias  = d_in[3];
    const void* a_src = d_in[4];
    const void* a_tgt = d_in[5];

    const int n_nodes = in_sizes[0] / 128;
    const int n_edges = in_sizes[1] / 2;
    const int nbk = (n_nodes + 255) >> 8;          // coarse buckets (tgt>>8)
    const int nba = (n_edges + 4095) / 4096;       // pass-A blocks

    char* p = (char*)d_ws;
    auto alloc = [&](size_t bytes) { char* q = p; p += (bytes + 255) & ~(size_t)255; return q; };
    int*   flags      = (int*)  alloc(256);
    void*  hp         = (void*) alloc((size_t)n_nodes * 128 * sizeof(float)); // bf16 table uses lower half
    u16*   Wt         = (u16*)  alloc(128 * 128 * sizeof(u16));
    float* ssrc       = (float*)alloc((size_t)n_nodes * 4 * sizeof(float));
    float* stgt       = (float*)alloc((size_t)n_nodes * 4 * sizeof(float));
    int*   offs       = (int*)  alloc(((size_t)n_nodes + 1) * sizeof(int));
    int*   bucket_cnt = (int*)  alloc((size_t)nbk * sizeof(int));
    int*   src_sorted = (int*)  alloc((size_t)n_edges * sizeof(int));

    // Bucket staging (8B/edge slot): overlay hp's (unused) upper half when it
    // fits — the bf16 table occupies only the lower n_nodes*256 bytes.
    size_t bkt_bytes = (size_t)nbk * BKT_CAP * sizeof(int2);
    int2* bkt;
    if (bkt_bytes <= (size_t)n_nodes * 128 * 2)
        bkt = (int2*)((char*)hp + (size_t)n_nodes * 128 * 2);
    else
        bkt = (int2*)alloc(bkt_bytes);

    k_init     <<<65, 256, 0, stream>>>((const u16*)h_in, (const int*)eidx, flags,
                                        (const u16*)W, Wt, bucket_cnt, nbk);
    k_bktA     <<<nba, 256, 0, stream>>>(eidx, flags, bucket_cnt, bkt,
                                         n_edges, n_nodes, nbk);
    k_bsort    <<<nbk, 256, 0, stream>>>(bucket_cnt, bkt, offs, src_sorted,
                                         n_edges, n_nodes, nbk);
    k_proj_mfma<<<(n_nodes + 63) / 64, 256, 0, stream>>>((const u16*)h_in, Wt, (const u16*)bias,
                                                         (const u16*)a_src, (const u16*)a_tgt,
                                                         flags, (u16*)hp, ssrc, stgt, n_nodes);
    k_proj_f32 <<<(n_nodes + 31) / 32, 256, 0, stream>>>((const float*)h_in, (const float*)W,
                                                         (const float*)bias, (const float*)a_src,
                                                         (const float*)a_tgt, flags, (u16*)hp,
                                                         ssrc, stgt, n_nodes);
    k_agg_csr  <<<(n_nodes + 3) / 4, 256, 0, stream>>>(offs, src_sorted, ssrc, stgt,
                                                       hp, d_out, flags, n_nodes);
}